// Round 13
// baseline (264.776 us; speedup 1.0000x reference)
//
#include <hip/hip_runtime.h>
#include <math.h>

#define BATCH  32
#define CH     3
#define H      512
#define W      512
#define KWIN   15
#define PAD    7
#define TH     32                 // output rows per wave
#define NRT    (TH + KWIN - 1)    // 46 input rows per wave, each loaded ONCE
#define STRIP  112                // output cols per wave (frame = 128 cols)
#define NSTRIP 5
#define NWAVES (BATCH * (H / TH) * NSTRIP)   // 2560
#define DEPTH  5                  // software-pipeline depth

static __device__ __forceinline__ float2 min2(float2 a, float2 b) {
    float2 r;
    r.x = fminf(a.x, b.x);
    r.y = fminf(a.y, b.y);
    return r;
}

// Fused dark-channel + 15x15 min-pool. Zero LDS/barriers; wave = 32 rows x
// 112 cols; lane owns 2 frame cols. Three-phase single-load van Herk:
//   A: rows v15..v29 -> hbuf[15]; prefix P1[j]=min(v15..v15+j); then in-place
//      suffix hbuf[i]=min(v[15+i]..v29); emit out15.
//   B: stream v14..v0 with running U; out r = min(U, P1[r-1]).
//   C: stream v30..v45 with running pp (from v30) and pp31 (from v31);
//      out 16+j = min(hbuf[j+1], pp); out30 = pp@44; out31 = pp31@45.
// Each of the 46 rows loaded exactly once -> row re-read 1.44x vs 1.875x in
// R12 (load instrs/L2 bytes -23%). Depth-5 pipeline keeps 15 b64 loads in
// flight. No __launch_bounds__ (R3/R5 allocator pathologies).
__global__ void dcp_fused9(const float* __restrict__ I, float* __restrict__ out) {
    const int wid = blockIdx.x * 4 + (threadIdx.x >> 6);
    const int L   = threadIdx.x & 63;
    const int s   = wid % NSTRIP;
    const int rb  = (wid / NSTRIP) % (H / TH);
    const int b   = wid / (NSTRIP * (H / TH));
    const int y0  = rb * TH;
    const int f   = s * STRIP - 8 + 2 * L;            // frame col (even)
    const int cl  = min(max(f, 0), W - 2);            // clamped, keeps 8B alignment
    const bool cv = (f >= 0) && (f < W);
    const bool st = (L >= 4) && (L <= 59) && (f < W); // lane stores output

    const float* base = I + (size_t)b * CH * H * W + cl;
    float* outb = out + (size_t)b * H * W;

    // flat step q -> v-row index: A: 15..29, B: 14..0, C: 30..45
    auto seqrow = [](int q) { return q < KWIN ? KWIN + q : (q < 2 * KWIN ? 29 - q : q); };

    auto loadrow = [&](int i, float2& A, float2& B, float2& C) {
        const int yc = min(max(y0 - PAD + i, 0), H - 1);
        const float* p = base + (size_t)yc * W;
        A = *(const float2*)(p);
        B = *(const float2*)(p + (size_t)H * W);
        C = *(const float2*)(p + (size_t)2 * H * W);
    };

    auto hcompute = [&](int i, float2 A, float2 B, float2 C) -> float2 {
        const int y = y0 - PAD + i;
        float2 d = min2(min2(A, B), C);
        const bool pad = (y < 0) || (y >= H) || !cv;
        d.x = pad ? INFINITY : d.x;                   // select, not branch
        d.y = pad ? INFINITY : d.y;
        const float pm = fminf(d.x, d.y);             // pair min (cols f,f+1)
        const float t2 = fminf(pm, __shfl_down(pm, 1));
        const float t4 = fminf(t2, __shfl_down(t2, 2));
        const float q7 = fminf(t4, __shfl_up(t4, 3)); // cols f-6..f+7
        float2 wv;
        wv.x = fminf(q7, __shfl_up(d.y, 4));          // + col f-7
        wv.y = fminf(q7, __shfl_down(d.x, 4));        // + col f+8
        return wv;
    };

    float2 Ab[DEPTH], Bb[DEPTH], Cb[DEPTH];
    #pragma unroll
    for (int j = 0; j < DEPTH; ++j)
        loadrow(seqrow(j), Ab[j], Bb[j], Cb[j]);

    float2 hbuf[KWIN];                                // raw h-min v15..29, then suffixes
    float2 P1[KWIN - 1];                              // prefix mins of v15..v28
    float2 U, pp, pp31;

    #pragma unroll
    for (int q = 0; q < NRT; ++q) {
        const int sl = q % DEPTH;                     // constant-folded (unrolled)
        const float2 h = hcompute(seqrow(q), Ab[sl], Bb[sl], Cb[sl]);
        if (q + DEPTH < NRT)
            loadrow(seqrow(q + DEPTH), Ab[sl], Bb[sl], Cb[sl]);

        if (q < KWIN) {                               // Phase A: v15..v29
            hbuf[q] = h;
            if (q == 0)            P1[0] = h;
            else if (q < KWIN - 1) P1[q] = min2(P1[q - 1], h);
            if (q == KWIN - 1) {                      // all 15 held: suffix in place
                #pragma unroll
                for (int i = KWIN - 2; i >= 0; --i)
                    hbuf[i] = min2(hbuf[i], hbuf[i + 1]);
                if (st) *(float2*)(outb + (size_t)(y0 + 15) * W + f) = hbuf[0];
            }
        } else if (q < 2 * KWIN) {                    // Phase B: v14..v0, outs 14..0
            const int r = 29 - q;
            U = (q == KWIN) ? h : min2(U, h);
            if (st) {
                if (r > 0)
                    *(float2*)(outb + (size_t)(y0 + r) * W + f) = min2(U, P1[r - 1]);
                else
                    *(float2*)(outb + (size_t)y0 * W + f) = U;
            }
        } else {                                      // Phase C: v30..v45, outs 15..31
            const int j = q - 2 * KWIN;               // 0..15
            pp = (j == 0) ? h : min2(pp, h);
            if (j == 1)      pp31 = h;
            else if (j > 1)  pp31 = min2(pp31, h);
            if (j <= 13) {
                if (st) *(float2*)(outb + (size_t)(y0 + 16 + j) * W + f) = min2(hbuf[j + 1], pp);
            } else if (j == 14) {                     // pp = min(v30..v44)
                if (st) *(float2*)(outb + (size_t)(y0 + 30) * W + f) = pp;
            } else {                                  // pp31 = min(v31..v45)
                if (st) *(float2*)(outb + (size_t)(y0 + 31) * W + f) = pp31;
            }
        }
    }
}

extern "C" void kernel_launch(void* const* d_in, const int* in_sizes, int n_in,
                              void* d_out, int out_size, void* d_ws, size_t ws_size,
                              hipStream_t stream) {
    const float* I = (const float*)d_in[0];
    // d_in[1] is k == 15, hard-coded (KWIN/PAD)
    float* out = (float*)d_out;
    dcp_fused9<<<dim3(NWAVES / 4), dim3(256), 0, stream>>>(I, out);
}

// Round 14
// 161.121 us; speedup vs baseline: 1.6433x; 1.6433x over previous
//
#include <hip/hip_runtime.h>
#include <math.h>

#define BATCH  32
#define CH     3
#define H      512
#define W      512
#define KWIN   15
#define PAD    7
#define TH     16                 // output rows per wave
#define NRR    (TH + KWIN - 1)    // 30 input rows per wave
#define STRIP  112                // output cols per wave (frame = 128 cols)
#define NSTRIP 5                  // ceil(512/112)
#define NWAVES (BATCH * (H / TH) * NSTRIP)   // 5120
#define DEPTH  5                  // software-pipeline depth (rows of loads in flight)

static __device__ __forceinline__ float2 min2(float2 a, float2 b) {
    float2 r;
    r.x = fminf(a.x, b.x);
    r.y = fminf(a.y, b.y);
    return r;
}

// BEST VERIFIED (R12, 159.9 us wall): fully fused dark-channel + 15x15
// min-pool. Zero LDS, zero barriers. Wave = 16 out rows x 112 out cols; lane
// owns 2 frame cols. Depth-5 software pipeline: 15 independent b64 loads
// (~7.5 KB/wave) in flight by construction. Loads unconditional (clamped row,
// +inf by select after the load). h-min via 5 shuffles/row.
// DO NOT: add __launch_bounds__ (R3: 20-VGPR serialization; R5: 64-VGPR
// spill), grow per-thread arrays beyond what a fully-unrolled loop keeps
// constant-indexed (R13: private arrays lowered to 80 KB LDS + scratch when
// the 46-iter loop failed to unroll), or split channel-min into its own pass
// (R11: +5-7 us from the extra dispatch + tmp round-trip).
__global__ void dcp_fused8(const float* __restrict__ I, float* __restrict__ out) {
    const int wid = blockIdx.x * 4 + (threadIdx.x >> 6);
    const int L   = threadIdx.x & 63;
    const int s   = wid % NSTRIP;
    const int rb  = (wid / NSTRIP) % (H / TH);
    const int b   = wid / (NSTRIP * (H / TH));
    const int y0  = rb * TH;
    const int f   = s * STRIP - 8 + 2 * L;            // frame col (even)
    const int cl  = min(max(f, 0), W - 2);            // clamped, keeps 8B alignment
    const bool cv = (f >= 0) && (f < W);
    const bool st = (L >= 4) && (L <= 59) && (f < W); // lane stores output

    const float* base = I + (size_t)b * CH * H * W + cl;
    float* outb = out + (size_t)b * H * W;

    // flat step q -> h-min row index: 15..29 (P-build), then 14..0 (U-stream)
    auto seqrow = [](int q) { return q < KWIN ? KWIN + q : 29 - q; };

    auto loadrow = [&](int i, float2& A, float2& B, float2& C) {
        const int yc = min(max(y0 - PAD + i, 0), H - 1);
        const float* p = base + (size_t)yc * W;
        A = *(const float2*)(p);
        B = *(const float2*)(p + (size_t)H * W);
        C = *(const float2*)(p + (size_t)2 * H * W);
    };

    auto hcompute = [&](int i, float2 A, float2 B, float2 C) -> float2 {
        const int y = y0 - PAD + i;
        float2 d = min2(min2(A, B), C);
        const bool pad = (y < 0) || (y >= H) || !cv;
        d.x = pad ? INFINITY : d.x;                   // select, not branch
        d.y = pad ? INFINITY : d.y;
        const float pm = fminf(d.x, d.y);             // pair min (cols f,f+1)
        const float t2 = fminf(pm, __shfl_down(pm, 1));
        const float t4 = fminf(t2, __shfl_down(t2, 2));
        const float q7 = fminf(t4, __shfl_up(t4, 3)); // cols f-6..f+7
        float2 wv;
        wv.x = fminf(q7, __shfl_up(d.y, 4));          // + col f-7
        wv.y = fminf(q7, __shfl_down(d.x, 4));        // + col f+8
        return wv;
    };

    float2 Ab[DEPTH], Bb[DEPTH], Cb[DEPTH];
    #pragma unroll
    for (int j = 0; j < DEPTH; ++j)
        loadrow(seqrow(j), Ab[j], Bb[j], Cb[j]);      // 15 loads issued up front

    float2 P[KWIN];
    float2 U;
    #pragma unroll
    for (int q = 0; q < NRR; ++q) {
        const int sl = q % DEPTH;                     // constant-folded (unrolled)
        const float2 h = hcompute(seqrow(q), Ab[sl], Bb[sl], Cb[sl]);
        if (q + DEPTH < NRR)
            loadrow(seqrow(q + DEPTH), Ab[sl], Bb[sl], Cb[sl]);

        if (q == 0) {
            P[0] = h;
        } else if (q < KWIN) {
            P[q] = min2(P[q - 1], h);                 // P[q] = min(rows 15..15+q)
            if (q == KWIN - 1 && st)
                *(float2*)(outb + (size_t)(y0 + 15) * W + f) = P[KWIN - 1];
        } else if (q == KWIN) {                       // row 14
            U = h;
            if (st) *(float2*)(outb + (size_t)(y0 + 14) * W + f) = min2(U, P[13]);
        } else if (q < NRR - 1) {                     // rows 13..1
            const int r = 29 - q;
            U = min2(U, h);
            if (st) *(float2*)(outb + (size_t)(y0 + r) * W + f) = min2(U, P[r - 1]);
        } else {                                      // row 0
            U = min2(U, h);
            if (st) *(float2*)(outb + (size_t)y0 * W + f) = U;
        }
    }
}

extern "C" void kernel_launch(void* const* d_in, const int* in_sizes, int n_in,
                              void* d_out, int out_size, void* d_ws, size_t ws_size,
                              hipStream_t stream) {
    const float* I = (const float*)d_in[0];
    // d_in[1] is k == 15, hard-coded (KWIN/PAD)
    float* out = (float*)d_out;
    dcp_fused8<<<dim3(NWAVES / 4), dim3(256), 0, stream>>>(I, out);
}